// Round 3
// baseline (662.157 us; speedup 1.0000x reference)
//
#include <hip/hip_runtime.h>
#include <math.h>

#define H 1024
#define SEQ 2048
#define BATCH 8
#define N_ENT 1000
#define TOPK 5
#define LN_EPS 1e-5f
#define NB_SMALL 64

using bf16x8 = __attribute__((ext_vector_type(8))) __bf16;
using f32x4  = __attribute__((ext_vector_type(4))) float;
#define AS1 __attribute__((address_space(1)))
#define AS3 __attribute__((address_space(3)))

// ---------- helpers ----------

// fast erf-GELU: Abramowitz-Stegun 7.1.26, |erf err| <= 1.5e-7, hw rcp/exp2
__device__ __forceinline__ float gelu_fast(float x) {
    float z = fabsf(x) * 0.70710678118654752440f;
    float t = __builtin_amdgcn_rcpf(fmaf(0.3275911f, z, 1.0f));
    float p = fmaf(fmaf(fmaf(fmaf(1.061405429f, t, -1.453152027f), t, 1.421413741f),
                        t, -0.284496736f), t, 0.254829592f) * t;
    float e = __builtin_amdgcn_exp2f(-z * z * 1.44269504088896f);
    float erfz = fmaf(-p, e, 1.0f);
    float s = copysignf(erfz, x);
    return 0.5f * x * (1.0f + s);
}

__device__ __forceinline__ float sigmoidf_(float x) {
    return 1.0f / (1.0f + expf(-x));
}

__device__ __forceinline__ unsigned short f2bf(float f) {
    unsigned int u = __float_as_uint(f);
    unsigned int r = (u + 0x7fffu + ((u >> 16) & 1u)) >> 16;  // RNE
    return (unsigned short)r;
}

__device__ float block_sum(float v, float* red) {
    for (int off = 32; off > 0; off >>= 1) v += __shfl_down(v, off, 64);
    int wid = threadIdx.x >> 6;
    int lane = threadIdx.x & 63;
    int nw = blockDim.x >> 6;
    if (lane == 0) red[wid] = v;
    __syncthreads();
    if (threadIdx.x == 0) {
        float s = 0.f;
        for (int i = 0; i < nw; ++i) s += red[i];
        red[0] = s;
    }
    __syncthreads();
    float r = red[0];
    __syncthreads();
    return r;
}

// device-scope sense barrier for NB_SMALL co-resident blocks.
// release: __syncthreads (drains block's mem ops) + agent fence.
// acquire: agent-scope atomic spin + fence, then __syncthreads.
__device__ __forceinline__ void gbar(unsigned* cnt, unsigned* gen) {
    __syncthreads();
    if (threadIdx.x == 0) {
        __threadfence();
        unsigned g = __hip_atomic_load(gen, __ATOMIC_RELAXED, __HIP_MEMORY_SCOPE_AGENT);
        unsigned a = __hip_atomic_fetch_add(cnt, 1u, __ATOMIC_ACQ_REL, __HIP_MEMORY_SCOPE_AGENT);
        if (a == NB_SMALL - 1) {
            __hip_atomic_store(cnt, 0u, __ATOMIC_RELAXED, __HIP_MEMORY_SCOPE_AGENT);
            __hip_atomic_fetch_add(gen, 1u, __ATOMIC_ACQ_REL, __HIP_MEMORY_SCOPE_AGENT);
        } else {
            while (__hip_atomic_load(gen, __ATOMIC_ACQUIRE, __HIP_MEMORY_SCOPE_AGENT) == g)
                __builtin_amdgcn_s_sleep(1);
        }
        __threadfence();
    }
    __syncthreads();
}

// ---------- conversion kernels ----------

__global__ void f2bf_kernel(const float* __restrict__ in, unsigned short* __restrict__ out, int n) {
    int i = (blockIdx.x * blockDim.x + threadIdx.x) * 4;
    if (i >= n) return;
    float4 v = *(const float4*)(in + i);
    ushort4 o;
    o.x = f2bf(v.x); o.y = f2bf(v.y); o.z = f2bf(v.z); o.w = f2bf(v.w);
    *(ushort4*)(out + i) = o;
}

// both weight transposes in one launch. bid<2048: ee_w1 (1024x2048); else ee_w2 (2048x1024)
__global__ void transpose_both_kernel(const float* __restrict__ w1, unsigned short* __restrict__ o1,
                                      const float* __restrict__ w2, unsigned short* __restrict__ o2) {
    __shared__ float tile[32][33];
    int bid = blockIdx.x;
    const float* in; unsigned short* out; int R, C, bx, by;
    if (bid < 2048) { in = w1; out = o1; R = 1024; C = 2048; bx = bid & 63; by = bid >> 6; }
    else { bid -= 2048; in = w2; out = o2; R = 2048; C = 1024; bx = bid & 31; by = bid >> 5; }
    int c0 = bx * 32, r0 = by * 32;
    int tx = threadIdx.x & 31, ty = threadIdx.x >> 5;
#pragma unroll
    for (int i = 0; i < 32; i += 8)
        tile[ty + i][tx] = in[(size_t)(r0 + ty + i) * C + c0 + tx];
    __syncthreads();
#pragma unroll
    for (int i = 0; i < 32; i += 8)
        out[(size_t)(c0 + ty + i) * R + r0 + tx] = f2bf(tile[tx][ty + i]);
}

// ---------- pooling phase 1 + fused hs->bf16 ----------

// grid (32, 8), block 256; float4 per thread per row
__global__ void pool1_kernel(const float* __restrict__ hs, float* __restrict__ part,
                             unsigned short* __restrict__ hsb) {
    int sc = blockIdx.x, b = blockIdx.y, t = threadIdx.x;
    size_t rowbase = (size_t)b * SEQ + sc * 64;
    const float* p = hs + rowbase * H + t * 4;
    float4 a = {0.f, 0.f, 0.f, 0.f};
    for (int s = 0; s < 64; ++s) {
        float4 v = *(const float4*)(p + (size_t)s * H);
        a.x += v.x; a.y += v.y; a.z += v.z; a.w += v.w;
        if (hsb) {
            ushort4 o;
            o.x = f2bf(v.x); o.y = f2bf(v.y); o.z = f2bf(v.z); o.w = f2bf(v.w);
            *(ushort4*)(hsb + (rowbase + s) * H + t * 4) = o;
        }
    }
    *(float4*)(part + ((size_t)b * 32 + sc) * H + t * 4) = a;
}

// ---------- the whole small path as ONE persistent kernel ----------
// 64 blocks x 256 threads, 13 device-scope barriers between stages.
// Stage->block maps mirror the previous discrete kernels exactly.

__device__ void mlp_partial_dev(const float* X, int ldx, const float* W, int N,
                                float* part, int jb, int ks, int KR, float* xs) {
    int t = threadIdx.x;
    int k0 = ks * KR;
    __syncthreads();
    for (int i = t; i < 8 * KR; i += 256) {
        int b = i / KR, k = i - b * KR;
        xs[b * KR + k] = X[(size_t)b * ldx + k0 + k];
    }
    __syncthreads();
    int j = jb * 256 + t;
    float acc[8] = {};
    for (int k = 0; k < KR; ++k) {
        float w = W[(size_t)(k0 + k) * N + j];
#pragma unroll
        for (int b = 0; b < 8; ++b) acc[b] = fmaf(xs[b * KR + k], w, acc[b]);
    }
#pragma unroll
    for (int b = 0; b < 8; ++b) part[((size_t)(ks * 8 + b)) * N + j] = acc[b];
}

__device__ void reduce_ln_256(const float* part, const float* bias, const float* g,
                              const float* be, float* out, int nks, int b, float* red) {
    int t = threadIdx.x;
    float4 s = *(const float4*)(bias + t * 4);
    for (int ks = 0; ks < nks; ++ks) {
        float4 p = *(const float4*)(part + (((size_t)(ks * 8 + b)) << 10) + t * 4);
        s.x += p.x; s.y += p.y; s.z += p.z; s.w += p.w;
    }
    float mu = block_sum(s.x + s.y + s.z + s.w, red) * (1.0f / H);
    float4 d = {s.x - mu, s.y - mu, s.z - mu, s.w - mu};
    float var = block_sum(d.x * d.x + d.y * d.y + d.z * d.z + d.w * d.w, red) * (1.0f / H);
    float inv = rsqrtf(var + LN_EPS);
    float4 gg = *(const float4*)(g + t * 4);
    float4 bb = *(const float4*)(be + t * 4);
    float4 o = {d.x * inv * gg.x + bb.x, d.y * inv * gg.y + bb.y,
                d.z * inv * gg.z + bb.z, d.w * inv * gg.w + bb.w};
    *(float4*)(out + ((size_t)b << 10) + t * 4) = o;
}

__global__ __launch_bounds__(256) void small_path_kernel(
    float* part,   // pool partials on entry; reused as mlp partial buffer
    float* pooled, float* h1r, float* h1n, float* xin, int* idx_i,
    const float* __restrict__ ent,
    const float* re_w1, const float* re_b1, const float* re_w2, const float* re_b2,
    const float* re_g, const float* re_be,
    const float* rn_w1, const float* rn_b1, const float* rn_w2, const float* rn_b2,
    const float* rn_g, const float* rn_be,
    const float* vn_w1, const float* vn_b1, const float* vn_w2, const float* vn_b2,
    float* rel, float* sims, float* tidx, float* retr, float* ro, float* vs,
    unsigned* bar) {
    __shared__ __align__(16) unsigned char smraw[33 * 1024];
    float* xs  = (float*)smraw;           // up to 8*128 floats (4 KB)
    float* rl  = (float*)smraw;           // 8192 floats (32 KB)
    float* tkv = (float*)smraw;           // 1024 floats
    float* trv = (float*)(smraw + 4096);  // 4 floats
    int*   tri = (int*)(smraw + 4112);    // 4 ints
    float* red = (float*)smraw;           // 32 floats

    unsigned* cnt = bar;
    unsigned* gen = bar + 1;
    const int bid = blockIdx.x;
    const int t = threadIdx.x;

    // ---- S0: pooled[8][1024] from pool partials ----
    {
        int gid = bid * 256 + t;
        if (gid < 8 * H) {
            int b = gid >> 10, h = gid & 1023;
            float s = 0.f;
            for (int sc = 0; sc < 32; ++sc) s += part[(((size_t)(b * 32 + sc)) << 10) + h];
            pooled[((size_t)b << 10) + h] = s * (1.0f / SEQ);
        }
    }
    gbar(cnt, gen);

    // ---- S1: re layer1 partial (KR=64, 4 jb x 16 ks = 64 blocks) ----
    mlp_partial_dev(pooled, H, re_w1, H, part, bid & 3, bid >> 2, 64, xs);
    gbar(cnt, gen);

    // ---- S2: re layer1 reduce+gelu (4 jb x 8 b = 32 blocks) ----
    if (bid < 32) {
        int jb = bid & 3, b = bid >> 2;
        int j = jb * 256 + t;
        float s = re_b1[j];
        for (int ks = 0; ks < 16; ++ks) s += part[((size_t)(ks * 8 + b)) * H + j];
        h1r[((size_t)b << 10) + j] = gelu_fast(s);
    }
    gbar(cnt, gen);

    // ---- S3: re layer2 partial ----
    mlp_partial_dev(h1r, H, re_w2, H, part, bid & 3, bid >> 2, 64, xs);
    gbar(cnt, gen);

    // ---- S4: re layer2 reduce + LN -> rel ----
    if (bid < 8) reduce_ln_256(part, re_b2, re_g, re_be, rel, 16, bid, red);
    gbar(cnt, gen);

    // ---- S5: sims (16 entities per block) ----
    {
        for (int i = t; i < 8 * H; i += 256) rl[i] = rel[i];
        __syncthreads();
        int widx = t >> 6, lane = t & 63;
        for (int r = 0; r < 4; ++r) {
            int e = bid * 16 + r * 4 + widx;
            if (e < N_ENT) {
                const float* ep = ent + (size_t)e * H;
                float ev[16];
#pragma unroll
                for (int i = 0; i < 16; ++i) ev[i] = ep[lane + i * 64];
#pragma unroll
                for (int b = 0; b < 8; ++b) {
                    float a = 0.f;
#pragma unroll
                    for (int i = 0; i < 16; ++i) a = fmaf(ev[i], rl[b * H + lane + i * 64], a);
                    for (int off = 32; off > 0; off >>= 1) a += __shfl_down(a, off, 64);
                    if (lane == 0) sims[b * N_ENT + e] = a;
                }
            }
        }
    }
    gbar(cnt, gen);

    // ---- S6: top-k (8 blocks) ----
    if (bid < 8) {
        int b = bid;
        for (int i = t; i < 1024; i += 256) tkv[i] = (i < N_ENT) ? sims[b * N_ENT + i] : -INFINITY;
        __syncthreads();
        for (int k = 0; k < TOPK; ++k) {
            float best = -INFINITY;
            int bi = 0x7fffffff;
            for (int i = t; i < 1024; i += 256) {
                float x = tkv[i];
                if (x > best || (x == best && i < bi)) { best = x; bi = i; }
            }
            for (int off = 32; off > 0; off >>= 1) {
                float ov = __shfl_down(best, off, 64);
                int oi = __shfl_down(bi, off, 64);
                if (ov > best || (ov == best && oi < bi)) { best = ov; bi = oi; }
            }
            if ((t & 63) == 0) { trv[t >> 6] = best; tri[t >> 6] = bi; }
            __syncthreads();
            if (t == 0) {
                for (int w = 1; w < 4; ++w)
                    if (trv[w] > trv[0] || (trv[w] == trv[0] && tri[w] < tri[0])) { trv[0] = trv[w]; tri[0] = tri[w]; }
                int sel = tri[0];
                tidx[b * TOPK + k] = (float)sel;
                idx_i[b * TOPK + k] = sel;
                tkv[sel] = -INFINITY;
            }
            __syncthreads();
        }
    }
    gbar(cnt, gen);

    // ---- S7: gather retrieved + build xin ----
    if (bid < 8) {
        int b = bid;
#pragma unroll
        for (int u = 0; u < 4; ++u) {
            int h = u * 256 + t;
            float acc = 0.f;
            for (int k = 0; k < TOPK; ++k) {
                float v = ent[(size_t)idx_i[b * TOPK + k] * H + h];
                retr[((size_t)(b * TOPK + k)) * H + h] = v;
                acc += v;
            }
            xin[(size_t)b * 3 * H + h] = acc * (1.0f / TOPK);
            xin[(size_t)b * 3 * H + H + h] = rel[b * H + h];
            xin[(size_t)b * 3 * H + 2 * H + h] = pooled[b * H + h];
        }
    }
    gbar(cnt, gen);

    // ---- S8: rn layer1 partial (KR=128, 8 jb x 24 ks = 192 units, 3 per block) ----
    for (int r = 0; r < 3; ++r) {
        int u = bid + 64 * r;
        mlp_partial_dev(xin, 3 * H, rn_w1, 2 * H, part, u & 7, u >> 3, 128, xs);
    }
    gbar(cnt, gen);

    // ---- S9: rn layer1 reduce+gelu (8 jb x 8 b = 64 blocks) ----
    {
        int jb = bid & 7, b = bid >> 3;
        int j = jb * 256 + t;
        float s = rn_b1[j];
        for (int ks = 0; ks < 24; ++ks) s += part[((size_t)(ks * 8 + b)) * 2048 + j];
        h1n[(size_t)b * 2048 + j] = gelu_fast(s);
    }
    gbar(cnt, gen);

    // ---- S10: rn layer2 partial (KR=128, 4 jb x 16 ks = 64 blocks) ----
    mlp_partial_dev(h1n, 2 * H, rn_w2, H, part, bid & 3, bid >> 2, 128, xs);
    gbar(cnt, gen);

    // ---- S11: rn layer2 reduce + LN -> ro ----
    if (bid < 8) reduce_ln_256(part, rn_b2, rn_g, rn_be, ro, 16, bid, red);
    gbar(cnt, gen);

    // ---- S12: vn layer1 partial (KR=128, 2 jb x 8 ks = 16 blocks) ----
    if (bid < 16) mlp_partial_dev(ro, H, vn_w1, 512, part, bid & 1, bid >> 1, 128, xs);
    else { __syncthreads(); __syncthreads(); }  // keep per-block syncthreads count irrelevant (different blocks)
    gbar(cnt, gen);

    // ---- S13: vn reduce + gelu + dot + sigmoid ----
    if (bid < 8) {
        int b = bid;
        float c = 0.f;
#pragma unroll
        for (int u = 0; u < 2; ++u) {
            int e = u * 256 + t;
            float s = vn_b1[e];
            for (int ks = 0; ks < 8; ++ks) s += part[((size_t)(ks * 8 + b)) * 512 + e];
            c += gelu_fast(s) * vn_w2[e];
        }
        float tot = block_sum(c, red);
        if (t == 0) vs[b] = sigmoidf_(tot + vn_b2[0]);
    }
}

// ---------- bf16 MFMA GEMM: 256x256 tile, BK=64, 8 waves, 4-phase schedule ----------
// (byte-identical schedule; vmcnt(6) counted pipeline, XOR-swizzled LDS reads,
// setprio around MFMA, bijective XCD swizzle.)
template <int GELU_BF16_OUT>
__global__ __launch_bounds__(512, 2) void gemm256_8ph(const unsigned short* __restrict__ A,
                                                      const unsigned short* __restrict__ Bt,
                                                      const float* __restrict__ bias,
                                                      void* __restrict__ Cout,
                                                      int M, int N, int K) {
    __shared__ __align__(16) unsigned short As[4][128 * 64];
    __shared__ __align__(16) unsigned short Bs[4][128 * 64];
    const int tid = threadIdx.x;
    const int lane = tid & 63;
    const int w = tid >> 6;
    const int wm2 = w >> 2;   // 0..1
    const int wn4 = w & 3;    // 0..3

    const int Np = N >> 8;
    const int nwg = gridDim.x;
    int bid = blockIdx.x;
    int s = bid;
    if ((nwg & 7) == 0) s = (bid & 7) * (nwg >> 3) + (bid >> 3);  // XCD-chunked, bijective
    const int m0 = (s / Np) << 8;
    const int n0 = (s % Np) << 8;

    const int nT = K >> 6;

    const int l7 = lane & 7;
    const int lrow0 = w * 16 + (lane >> 3);
    const int lrow1 = lrow0 + 8;
    const int kel0 = ((l7 ^ (lrow0 & 7)) << 3);   // pre-swizzled k element offset
    const int kel1 = ((l7 ^ (lrow1 & 7)) << 3);
    const unsigned short* pa0 = A + (size_t)(m0 + lrow0) * K + kel0;
    const unsigned short* pa1 = A + (size_t)(m0 + lrow1) * K + kel1;
    const unsigned short* pb0 = Bt + (size_t)(n0 + lrow0) * K + kel0;
    const unsigned short* pb1 = Bt + (size_t)(n0 + lrow1) * K + kel1;
    const size_t halfstep = (size_t)128 * K;
    const int dst0 = (w * 16) * 64;
    const int dst1 = dst0 + 8 * 64;

    auto stageA = [&](int t, int half) {
        if (t >= nT) return;
        int slot = (2 * t + half) & 3;
        int koff = t << 6;
        __builtin_amdgcn_global_load_lds((AS1 void*)(pa0 + half * halfstep + koff),
                                         (AS3 void*)(&As[slot][dst0]), 16, 0, 0);
        __builtin_amdgcn_global_load_lds((AS1 void*)(pa1 + half * halfstep + koff),
                                         (AS3 void*)(&As[slot][dst1]), 16, 0, 0);
    };
    auto stageB = [&](int t, int half) {
        if (t >= nT) return;
        int slot = (2 * t + half) & 3;
        int koff = t << 6;
        __builtin_amdgcn_global_load_lds((AS1 void*)(pb0 + half * halfstep + koff),
                                         (AS3 void*)(&Bs[slot][dst0]), 16, 0, 0);
        __builtin_amdgcn_global_load_lds((AS1 void*)(pb1 + half * halfstep + koff),
                                         (AS3 void*)(&Bs[slot][dst1]), 16, 0, 0);
    };

    const int arow = lane & 15;
    const int xk0 = (((lane >> 4) << 4)) ^ (l7 << 4);
    const int xk1 = (64 + ((lane >> 4) << 4)) ^ (l7 << 4);
    auto ldf = [&](const unsigned short* slotbase, int rowbase, int xk) -> bf16x8 {
        return *(const bf16x8*)((const char*)slotbase + (rowbase + arow) * 128 + xk);
    };

    f32x4 acc[8][4] = {};

    stageA(0, 0); stageA(0, 1); stageB(0, 0); stageB(0, 1);
    asm volatile("s_waitcnt vmcnt(4)" ::: "memory");
    stageA(1, 0); stageB(1, 0); stageB(1, 1);
    asm volatile("s_waitcnt vmcnt(6)" ::: "memory");
    __builtin_amdgcn_s_barrier();

    bf16x8 af0[4][2], af1[4][2], bf0[2][2], bf1[2][2];

    for (int T = 0; T < nT; ++T) {
        const unsigned short* Aslot0 = As[(2 * T) & 3];
        const unsigned short* Aslot1 = As[(2 * T + 1) & 3];
        const unsigned short* Bslot0 = Bs[(2 * T) & 3];
        const unsigned short* Bslot1 = Bs[(2 * T + 1) & 3];

        // ---- phase 1: (ih0, jh0) ----
#pragma unroll
        for (int ii = 0; ii < 4; ++ii) {
            af0[ii][0] = ldf(Aslot0, ii * 32 + wm2 * 16, xk0);
            af0[ii][1] = ldf(Aslot0, ii * 32 + wm2 * 16, xk1);
        }
#pragma unroll
        for (int jj = 0; jj < 2; ++jj) {
            bf0[jj][0] = ldf(Bslot0, jj * 64 + wn4 * 16, xk0);
            bf0[jj][1] = ldf(Bslot0, jj * 64 + wn4 * 16, xk1);
        }
        stageA(T + 1, 1);
        __builtin_amdgcn_s_barrier();
        __builtin_amdgcn_s_setprio(1);
#pragma unroll
        for (int ii = 0; ii < 4; ++ii)
#pragma unroll
            for (int jj = 0; jj < 2; ++jj) {
                acc[ii][jj] = __builtin_amdgcn_mfma_f32_16x16x32_bf16(af0[ii][0], bf0[jj][0], acc[ii][jj], 0, 0, 0);
                acc[ii][jj] = __builtin_amdgcn_mfma_f32_16x16x32_bf16(af0[ii][1], bf0[jj][1], acc[ii][jj], 0, 0, 0);
            }
        __builtin_amdgcn_s_setprio(0);
        __builtin_amdgcn_s_barrier();

        // ---- phase 2: (ih0, jh1) ----
#pragma unroll
        for (int jj = 0; jj < 2; ++jj) {
            bf1[jj][0] = ldf(Bslot1, jj * 64 + wn4 * 16, xk0);
            bf1[jj][1] = ldf(Bslot1, jj * 64 + wn4 * 16, xk1);
        }
        stageA(T + 2, 0);
        __builtin_amdgcn_s_barrier();
        __builtin_amdgcn_s_setprio(1);
#pragma unroll
        for (int ii = 0; ii < 4; ++ii)
#pragma unroll
            for (int jj = 0; jj < 2; ++jj) {
                acc[ii][2 + jj] = __builtin_amdgcn_mfma_f32_16x16x32_bf16(af0[ii][0], bf1[jj][0], acc[ii][2 + jj], 0, 0, 0);
                acc[ii][2 + jj] = __builtin_amdgcn_mfma_f32_16x16x32_bf16(af0[ii][1], bf1[jj][1], acc[ii][2 + jj], 0, 0, 0);
            }
        __builtin_amdgcn_s_setprio(0);
        __builtin_amdgcn_s_barrier();

        // ---- phase 3: (ih1, jh0) ----
#pragma unroll
        for (int ii = 0; ii < 4; ++ii) {
            af1[ii][0] = ldf(Aslot1, ii * 32 + wm2 * 16, xk0);
            af1[ii][1] = ldf(Aslot1, ii * 32 + wm2 * 16, xk1);
        }
        stageB(T + 2, 0);
        __builtin_amdgcn_s_barrier();
        __builtin_amdgcn_s_setprio(1);
#pragma unroll
        for (int ii = 0; ii < 4; ++ii)
#pragma unroll
            for (int jj = 0; jj < 2; ++jj) {
                acc[4 + ii][jj] = __builtin_amdgcn_mfma_f32_16x16x32_bf16(af1[ii][0], bf0[jj][0], acc[4 + ii][jj], 0, 0, 0);
                acc[4 + ii][jj] = __builtin_amdgcn_mfma_f32_16x16x32_bf16(af1[ii][1], bf0[jj][1], acc[4 + ii][jj], 0, 0, 0);
            }
        __builtin_amdgcn_s_setprio(0);
        __builtin_amdgcn_s_barrier();

        // ---- phase 4: (ih1, jh1); gate for tile T+1 ----
        stageB(T + 2, 1);
        if (T + 3 <= nT) {
            asm volatile("s_waitcnt vmcnt(6)" ::: "memory");
        } else {
            asm volatile("s_waitcnt vmcnt(0)" ::: "memory");
        }
        __builtin_amdgcn_s_barrier();
        __builtin_amdgcn_s_setprio(1);
#pragma unroll
        for (int ii = 0; ii < 4; ++ii)
#pragma unroll
            for (int jj = 0; jj < 2; ++jj) {
                acc[4 + ii][2 + jj] = __builtin_amdgcn_mfma_f32_16x16x32_bf16(af1[ii][0], bf1[jj][0], acc[4 + ii][2 + jj], 0, 0, 0);
                acc[4 + ii][2 + jj] = __builtin_amdgcn_mfma_f32_16x16x32_bf16(af1[ii][1], bf1[jj][1], acc[4 + ii][2 + jj], 0, 0, 0);
            }
        __builtin_amdgcn_s_setprio(0);
        __builtin_amdgcn_s_barrier();
    }

    const int cn = lane & 15;
    const int rbase = (lane >> 4) * 4;
#pragma unroll
    for (int i = 0; i < 8; ++i) {
        int mbase = m0 + (i >> 2) * 128 + (i & 3) * 32 + wm2 * 16 + rbase;
#pragma unroll
        for (int j = 0; j < 4; ++j) {
            int n = n0 + (j >> 1) * 128 + (j & 1) * 64 + wn4 * 16 + cn;
            float bv = bias[n];
#pragma unroll
            for (int r = 0; r < 4; ++r) {
                float c = acc[i][j][r] + bv;
                if (GELU_BF16_OUT) {
                    c = gelu_fast(c);
                    ((unsigned short*)Cout)[(size_t)(mbase + r) * N + n] = f2bf(c);
                } else {
                    ((float*)Cout)[(size_t)(mbase + r) * N + n] = c;
                }
            }
        }
    }
}

// per-row LayerNorm in place, float4. grid rows, block 256
__global__ void ln_rows_kernel(float* __restrict__ x, const float* __restrict__ g,
                               const float* __restrict__ beta) {
    __shared__ float red[32];
    float* p = x + (size_t)blockIdx.x * H;
    int t = threadIdx.x;
    float4 v = *(const float4*)(p + t * 4);
    float s = v.x + v.y + v.z + v.w;
    float mu = block_sum(s, red) * (1.0f / H);
    float4 d = { v.x - mu, v.y - mu, v.z - mu, v.w - mu };
    float d2 = d.x * d.x + d.y * d.y + d.z * d.z + d.w * d.w;
    float var = block_sum(d2, red) * (1.0f / H);
    float inv = rsqrtf(var + LN_EPS);
    float4 gg = *(const float4*)(g + t * 4);
    float4 bb = *(const float4*)(beta + t * 4);
    float4 o = { d.x * inv * gg.x + bb.x, d.y * inv * gg.y + bb.y,
                 d.z * inv * gg.z + bb.z, d.w * inv * gg.w + bb.w };
    *(float4*)(p + t * 4) = o;
}

// ---------- launch ----------

extern "C" void kernel_launch(void* const* d_in, const int* in_sizes, int n_in,
                              void* d_out, int out_size, void* d_ws, size_t ws_size,
                              hipStream_t stream) {
    const float* hs     = (const float*)d_in[0];
    const float* ent    = (const float*)d_in[1];
    const float* ee_w1  = (const float*)d_in[2];
    const float* ee_b1  = (const float*)d_in[3];
    const float* ee_w2  = (const float*)d_in[4];
    const float* ee_b2  = (const float*)d_in[5];
    const float* ee_g   = (const float*)d_in[6];
    const float* ee_be  = (const float*)d_in[7];
    const float* re_w1  = (const float*)d_in[8];
    const float* re_b1  = (const float*)d_in[9];
    const float* re_w2  = (const float*)d_in[10];
    const float* re_b2  = (const float*)d_in[11];
    const float* re_g   = (const float*)d_in[12];
    const float* re_be  = (const float*)d_in[13];
    const float* rn_w1  = (const float*)d_in[14];
    const float* rn_b1  = (const float*)d_in[15];
    const float* rn_w2  = (const float*)d_in[16];
    const float* rn_b2  = (const float*)d_in[17];
    const float* rn_g   = (const float*)d_in[18];
    const float* rn_be  = (const float*)d_in[19];
    const float* vn_w1  = (const float*)d_in[20];
    const float* vn_b1  = (const float*)d_in[21];
    const float* vn_w2  = (const float*)d_in[22];
    const float* vn_b2  = (const float*)d_in[23];

    float* out = (float*)d_out;
    float* ef   = out;
    float* rel  = ef + (size_t)BATCH * SEQ * H;
    float* retr = rel + BATCH * H;
    float* sims = retr + BATCH * TOPK * H;
    float* tidx = sims + BATCH * N_ENT;
    float* ro   = tidx + BATCH * TOPK;
    float* vs   = ro + BATCH * H;

    float* ws = (float*)d_ws;
    size_t o = 0;
    float* pooled = ws + o; o += 8192;
    int*   idx_i  = (int*)(ws + o); o += 64;
    unsigned* bar = (unsigned*)(ws + o); o += 16;
    float* xin    = ws + o; o += 8 * 3 * H;
    float* h1r    = ws + o; o += 8 * H;
    float* h1n    = ws + o; o += 8 * 2 * H;
    float* part   = ws + o; o += 24 * 8 * 2048;   // 393216 floats, reused by all stages
    unsigned short* w1t = (unsigned short*)(ws + o); o += (2048 * 1024) / 2;
    unsigned short* w2t = (unsigned short*)(ws + o); o += (2048 * 1024) / 2;
    unsigned short* hsb = (unsigned short*)(ws + o);

    long long avail = (long long)(ws_size / 4) - (long long)o;
    int chunk = (int)(avail / 1536);  // per row: 512 (hsb) + 1024 (mid) floats
    chunk &= ~255;                    // 256-row tiles
    int total = BATCH * SEQ;
    if (chunk > total) chunk = total;
    if (chunk < 256) chunk = 256;
    bool full = (chunk >= total);
    unsigned short* midb = hsb + (size_t)chunk * H;

    // barrier state must start zeroed (stream-ordered, capture-legal)
    hipMemsetAsync(bar, 0, 2 * sizeof(unsigned), stream);

    // pooling phase 1 (+ hs->bf16 fused when ws fits all rows)
    pool1_kernel<<<dim3(32, BATCH), 256, 0, stream>>>(hs, part, full ? hsb : nullptr);

    // weight prep (both transposes, one launch)
    transpose_both_kernel<<<4096, 256, 0, stream>>>(ee_w1, w1t, ee_w2, w2t);

    // the whole small path in ONE persistent kernel (64 blocks, device barriers)
    small_path_kernel<<<NB_SMALL, 256, 0, stream>>>(
        part, pooled, h1r, h1n, xin, idx_i, ent,
        re_w1, re_b1, re_w2, re_b2, re_g, re_be,
        rn_w1, rn_b1, rn_w2, rn_b2, rn_g, rn_be,
        vn_w1, vn_b1, vn_w2, vn_b2,
        rel, sims, tidx, retr, ro, vs, bar);

    // entity encoder (bf16 MFMA, 256^2 pipeline)
    for (int r0 = 0; r0 < total; r0 += chunk) {
        int m = total - r0;
        if (m > chunk) m = chunk;
        if (!full) {
            int nconv = m * H;
            f2bf_kernel<<<(nconv / 4 + 255) / 256, 256, 0, stream>>>(hs + (size_t)r0 * H, hsb, nconv);
        }
        unsigned short* a1 = full ? (hsb + (size_t)r0 * H) : hsb;
        gemm256_8ph<1><<<(m / 256) * (2048 / 256), 512, 0, stream>>>(a1, w1t, ee_b1, midb,
                                                                     m, 2048, 1024);
        gemm256_8ph<0><<<(m / 256) * (1024 / 256), 512, 0, stream>>>(midb, w2t, ee_b2,
                                                                     ef + (size_t)r0 * H,
                                                                     m, 1024, 2048);
    }
    ln_rows_kernel<<<total, 256, 0, stream>>>(ef, ee_g, ee_be);
}

// Round 4
// 534.545 us; speedup vs baseline: 1.2387x; 1.2387x over previous
//
#include <hip/hip_runtime.h>
#include <math.h>

#define H 1024
#define SEQ 2048
#define BATCH 8
#define N_ENT 1000
#define TOPK 5
#define LN_EPS 1e-5f

using bf16x8 = __attribute__((ext_vector_type(8))) __bf16;
using f32x4  = __attribute__((ext_vector_type(4))) float;
#define AS1 __attribute__((address_space(1)))
#define AS3 __attribute__((address_space(3)))

// ---------- helpers ----------

// fast erf-GELU: Abramowitz-Stegun 7.1.26, |erf err| <= 1.5e-7, hw rcp/exp2
__device__ __forceinline__ float gelu_fast(float x) {
    float z = fabsf(x) * 0.70710678118654752440f;
    float t = __builtin_amdgcn_rcpf(fmaf(0.3275911f, z, 1.0f));
    float p = fmaf(fmaf(fmaf(fmaf(1.061405429f, t, -1.453152027f), t, 1.421413741f),
                        t, -0.284496736f), t, 0.254829592f) * t;
    float e = __builtin_amdgcn_exp2f(-z * z * 1.44269504088896f);
    float erfz = fmaf(-p, e, 1.0f);
    float s = copysignf(erfz, x);
    return 0.5f * x * (1.0f + s);
}

__device__ __forceinline__ float sigmoidf_(float x) {
    return 1.0f / (1.0f + expf(-x));
}

__device__ __forceinline__ unsigned short f2bf(float f) {
    unsigned int u = __float_as_uint(f);
    unsigned int r = (u + 0x7fffu + ((u >> 16) & 1u)) >> 16;  // RNE
    return (unsigned short)r;
}

__device__ float block_sum(float v, float* red) {
    for (int off = 32; off > 0; off >>= 1) v += __shfl_down(v, off, 64);
    int wid = threadIdx.x >> 6;
    int lane = threadIdx.x & 63;
    int nw = blockDim.x >> 6;
    if (lane == 0) red[wid] = v;
    __syncthreads();
    if (threadIdx.x == 0) {
        float s = 0.f;
        for (int i = 0; i < nw; ++i) s += red[i];
        red[0] = s;
    }
    __syncthreads();
    float r = red[0];
    __syncthreads();
    return r;
}

// ---------- conversion kernels ----------

__global__ void f2bf_kernel(const float* __restrict__ in, unsigned short* __restrict__ out, int n) {
    int i = (blockIdx.x * blockDim.x + threadIdx.x) * 4;
    if (i >= n) return;
    float4 v = *(const float4*)(in + i);
    ushort4 o;
    o.x = f2bf(v.x); o.y = f2bf(v.y); o.z = f2bf(v.z); o.w = f2bf(v.w);
    *(ushort4*)(out + i) = o;
}

// both weight transposes in one launch. bid<2048: ee_w1 (1024x2048); else ee_w2 (2048x1024)
__global__ void transpose_both_kernel(const float* __restrict__ w1, unsigned short* __restrict__ o1,
                                      const float* __restrict__ w2, unsigned short* __restrict__ o2) {
    __shared__ float tile[32][33];
    int bid = blockIdx.x;
    const float* in; unsigned short* out; int R, C, bx, by;
    if (bid < 2048) { in = w1; out = o1; R = 1024; C = 2048; bx = bid & 63; by = bid >> 6; }
    else { bid -= 2048; in = w2; out = o2; R = 2048; C = 1024; bx = bid & 31; by = bid >> 5; }
    int c0 = bx * 32, r0 = by * 32;
    int tx = threadIdx.x & 31, ty = threadIdx.x >> 5;
#pragma unroll
    for (int i = 0; i < 32; i += 8)
        tile[ty + i][tx] = in[(size_t)(r0 + ty + i) * C + c0 + tx];
    __syncthreads();
#pragma unroll
    for (int i = 0; i < 32; i += 8)
        out[(size_t)(c0 + ty + i) * R + r0 + tx] = f2bf(tile[tx][ty + i]);
}

// ---------- pooling (2-phase) + fused hs->bf16 ----------

// grid (32, 8), block 256; float4 per thread per row
__global__ void pool1_kernel(const float* __restrict__ hs, float* __restrict__ part,
                             unsigned short* __restrict__ hsb) {
    int sc = blockIdx.x, b = blockIdx.y, t = threadIdx.x;
    size_t rowbase = (size_t)b * SEQ + sc * 64;
    const float* p = hs + rowbase * H + t * 4;
    float4 a = {0.f, 0.f, 0.f, 0.f};
    for (int s = 0; s < 64; ++s) {
        float4 v = *(const float4*)(p + (size_t)s * H);
        a.x += v.x; a.y += v.y; a.z += v.z; a.w += v.w;
        if (hsb) {
            ushort4 o;
            o.x = f2bf(v.x); o.y = f2bf(v.y); o.z = f2bf(v.z); o.w = f2bf(v.w);
            *(ushort4*)(hsb + (rowbase + s) * H + t * 4) = o;
        }
    }
    *(float4*)(part + ((size_t)b * 32 + sc) * H + t * 4) = a;
}

// grid 8, block 256; float4 cols per thread
__global__ void pool2_kernel(const float* __restrict__ part, float* __restrict__ pooled) {
    int b = blockIdx.x, t = threadIdx.x;
    float4 s = {0.f, 0.f, 0.f, 0.f};
    for (int sc = 0; sc < 32; ++sc) {
        float4 v = *(const float4*)(part + ((size_t)b * 32 + sc) * H + t * 4);
        s.x += v.x; s.y += v.y; s.z += v.z; s.w += v.w;
    }
    float4 o = {s.x * (1.0f / SEQ), s.y * (1.0f / SEQ), s.z * (1.0f / SEQ), s.w * (1.0f / SEQ)};
    *(float4*)(pooled + (size_t)b * H + t * 4) = o;
}

// ---------- small MLP path: k-split partial + fused-reduce partial ----------

// partial[ks][b][j] = sum_{k in ks-range} X[b][k] * W[k][j]
template <int KRANGE>
__global__ void mlp_partial_kernel(const float* __restrict__ X, int ldx,
                                   const float* __restrict__ W, int N,
                                   float* __restrict__ part) {
    __shared__ float xs[8][KRANGE];
    int jb = blockIdx.x, ks = blockIdx.y, t = threadIdx.x;
    int k0 = ks * KRANGE;
    for (int i = t; i < 8 * KRANGE; i += 256) {
        int b = i / KRANGE, k = i % KRANGE;
        xs[b][k] = X[(size_t)b * ldx + k0 + k];
    }
    __syncthreads();
    int j = jb * 256 + t;
    float acc[8] = {};
    for (int k = 0; k < KRANGE; ++k) {
        float w = W[(size_t)(k0 + k) * N + j];
#pragma unroll
        for (int b = 0; b < 8; ++b) acc[b] = fmaf(xs[b][k], w, acc[b]);
    }
#pragma unroll
    for (int b = 0; b < 8; ++b) part[((size_t)(ks * 8 + b)) * N + j] = acc[b];
}

// same, but X = gelu(b1 + sum_q Pprev[q][b][col]) computed on the fly (fused reduce+gelu)
template <int KRANGE>
__global__ void mlp_partial_fused_kernel(const float* __restrict__ Pprev, int ldp, int nksp,
                                         const float* __restrict__ b1,
                                         const float* __restrict__ W, int N,
                                         float* __restrict__ part) {
    __shared__ float xs[8][KRANGE];
    int jb = blockIdx.x, ks = blockIdx.y, t = threadIdx.x;
    int k0 = ks * KRANGE;
    for (int i = t; i < 8 * KRANGE; i += 256) {
        int b = i / KRANGE, k = i % KRANGE;
        int col = k0 + k;
        float s = b1[col];
        for (int q = 0; q < nksp; ++q) s += Pprev[((size_t)(q * 8 + b)) * ldp + col];
        xs[b][k] = gelu_fast(s);
    }
    __syncthreads();
    int j = jb * 256 + t;
    float acc[8] = {};
    for (int k = 0; k < KRANGE; ++k) {
        float w = W[(size_t)(k0 + k) * N + j];
#pragma unroll
        for (int b = 0; b < 8; ++b) acc[b] = fmaf(xs[b][k], w, acc[b]);
    }
#pragma unroll
    for (int b = 0; b < 8; ++b) part[((size_t)(ks * 8 + b)) * N + j] = acc[b];
}

__global__ void mlp_reduce_ln_kernel(const float* __restrict__ part, const float* __restrict__ bias,
                                     const float* __restrict__ g, const float* __restrict__ be,
                                     float* __restrict__ out, int nks) {
    __shared__ float red[32];
    int b = blockIdx.x, t = threadIdx.x;
    float s = bias[t];
    for (int ks = 0; ks < nks; ++ks) s += part[((size_t)(ks * 8 + b)) * H + t];
    float mu = block_sum(s, red) * (1.0f / H);
    float d = s - mu;
    float var = block_sum(d * d, red) * (1.0f / H);
    out[(size_t)b * H + t] = d * rsqrtf(var + LN_EPS) * g[t] + be[t];
}

// ---------- sims / topk / gather+concat / validation tail ----------

__global__ void sim_kernel(const float* __restrict__ rel, const float* __restrict__ ent,
                           float* __restrict__ sims) {
    __shared__ float rl[8 * H];
    int t = threadIdx.x;
    for (int i = t; i < 8 * H; i += 256) rl[i] = rel[i];
    __syncthreads();
    int e = blockIdx.x * 4 + (t >> 6);
    int lane = t & 63;
    float ev[16];
    const float* ep = ent + (size_t)e * H;
#pragma unroll
    for (int i = 0; i < 16; ++i) ev[i] = ep[lane + i * 64];
#pragma unroll
    for (int b = 0; b < 8; ++b) {
        float a = 0.f;
#pragma unroll
        for (int i = 0; i < 16; ++i) a = fmaf(ev[i], rl[b * H + lane + i * 64], a);
        for (int off = 32; off > 0; off >>= 1) a += __shfl_down(a, off, 64);
        if (lane == 0) sims[b * N_ENT + e] = a;
    }
}

__global__ void topk_kernel(const float* __restrict__ sims, float* __restrict__ out_idx_f,
                            int* __restrict__ idx_i) {
    __shared__ float v[1024];
    __shared__ float rv[4];
    __shared__ int ri[4];
    int b = blockIdx.x, t = threadIdx.x;
    for (int i = t; i < 1024; i += 256) v[i] = (i < N_ENT) ? sims[b * N_ENT + i] : -INFINITY;
    __syncthreads();
    for (int k = 0; k < TOPK; ++k) {
        float best = -INFINITY;
        int bi = 0x7fffffff;
        for (int i = t; i < 1024; i += 256) {
            float x = v[i];
            if (x > best || (x == best && i < bi)) { best = x; bi = i; }
        }
        for (int off = 32; off > 0; off >>= 1) {
            float ov = __shfl_down(best, off, 64);
            int oi = __shfl_down(bi, off, 64);
            if (ov > best || (ov == best && oi < bi)) { best = ov; bi = oi; }
        }
        if ((t & 63) == 0) { rv[t >> 6] = best; ri[t >> 6] = bi; }
        __syncthreads();
        if (t == 0) {
            for (int w = 1; w < 4; ++w)
                if (rv[w] > rv[0] || (rv[w] == rv[0] && ri[w] < ri[0])) { rv[0] = rv[w]; ri[0] = ri[w]; }
            int sel = ri[0];
            out_idx_f[b * TOPK + k] = (float)sel;
            idx_i[b * TOPK + k] = sel;
            v[sel] = -INFINITY;
        }
        __syncthreads();
    }
}

__global__ void gather_concat_kernel(const float* __restrict__ ent, const int* __restrict__ idx,
                                     const float* __restrict__ rel, const float* __restrict__ pooled,
                                     float* __restrict__ retrieved, float* __restrict__ xin) {
    int b = blockIdx.x, h = threadIdx.x;
    float acc = 0.f;
    for (int k = 0; k < TOPK; ++k) {
        float v = ent[(size_t)idx[b * TOPK + k] * H + h];
        retrieved[((size_t)b * TOPK + k) * H + h] = v;
        acc += v;
    }
    float* xb = xin + (size_t)b * 3 * H;
    xb[h] = acc * (1.0f / TOPK);
    xb[H + h] = rel[b * H + h];
    xb[2 * H + h] = pooled[b * H + h];
}

// partial sums of vn layer1 in, gelu+dot+sigmoid.  grid 8, block 512
__global__ void vn_final_kernel(const float* __restrict__ part, const float* __restrict__ b1,
                                const float* __restrict__ w2, const float* __restrict__ b2,
                                float* __restrict__ vs, int nks) {
    __shared__ float red[32];
    int b = blockIdx.x, t = threadIdx.x;
    float s = b1[t];
    for (int ks = 0; ks < nks; ++ks) s += part[((size_t)(ks * 8 + b)) * 512 + t];
    float c = gelu_fast(s) * w2[t];
    float tot = block_sum(c, red);
    if (t == 0) vs[b] = sigmoidf_(tot + b2[0]);
}

// ---------- bf16 MFMA GEMM: 256x256 tile, BK=64, 8 waves, 4-phase schedule ----------
// K-loop identical to round-1/2 (vmcnt(6) counted pipeline, XOR-swizzled LDS reads,
// setprio around MFMA, bijective XCD swizzle).  NEW: LDS-staged vectorized epilogue
// (C-tile through the freed 128KB LDS, dwordx4 coalesced stores, 2-way-swz writes).
template <int GELU_BF16_OUT>
__global__ __launch_bounds__(512, 2) void gemm256_8ph(const unsigned short* __restrict__ A,
                                                      const unsigned short* __restrict__ Bt,
                                                      const float* __restrict__ bias,
                                                      void* __restrict__ Cout,
                                                      int M, int N, int K) {
    __shared__ __align__(16) unsigned short smem[65536];   // 128 KB
    unsigned short (*As)[8192] = (unsigned short(*)[8192])smem;
    unsigned short (*Bs)[8192] = (unsigned short(*)[8192])(smem + 32768);
    const int tid = threadIdx.x;
    const int lane = tid & 63;
    const int w = tid >> 6;
    const int wm2 = w >> 2;   // 0..1
    const int wn4 = w & 3;    // 0..3

    const int Np = N >> 8;
    const int nwg = gridDim.x;
    int bid = blockIdx.x;
    int s = bid;
    if ((nwg & 7) == 0) s = (bid & 7) * (nwg >> 3) + (bid >> 3);  // XCD-chunked, bijective
    const int m0 = (s / Np) << 8;
    const int n0 = (s % Np) << 8;

    const int nT = K >> 6;

    const int l7 = lane & 7;
    const int lrow0 = w * 16 + (lane >> 3);
    const int lrow1 = lrow0 + 8;
    const int kel0 = ((l7 ^ (lrow0 & 7)) << 3);   // pre-swizzled k element offset
    const int kel1 = ((l7 ^ (lrow1 & 7)) << 3);
    const unsigned short* pa0 = A + (size_t)(m0 + lrow0) * K + kel0;
    const unsigned short* pa1 = A + (size_t)(m0 + lrow1) * K + kel1;
    const unsigned short* pb0 = Bt + (size_t)(n0 + lrow0) * K + kel0;
    const unsigned short* pb1 = Bt + (size_t)(n0 + lrow1) * K + kel1;
    const size_t halfstep = (size_t)128 * K;
    const int dst0 = (w * 16) * 64;
    const int dst1 = dst0 + 8 * 64;

    auto stageA = [&](int t, int half) {
        if (t >= nT) return;
        int slot = (2 * t + half) & 3;
        int koff = t << 6;
        __builtin_amdgcn_global_load_lds((AS1 void*)(pa0 + half * halfstep + koff),
                                         (AS3 void*)(&As[slot][dst0]), 16, 0, 0);
        __builtin_amdgcn_global_load_lds((AS1 void*)(pa1 + half * halfstep + koff),
                                         (AS3 void*)(&As[slot][dst1]), 16, 0, 0);
    };
    auto stageB = [&](int t, int half) {
        if (t >= nT) return;
        int slot = (2 * t + half) & 3;
        int koff = t << 6;
        __builtin_amdgcn_global_load_lds((AS1 void*)(pb0 + half * halfstep + koff),
                                         (AS3 void*)(&Bs[slot][dst0]), 16, 0, 0);
        __builtin_amdgcn_global_load_lds((AS1 void*)(pb1 + half * halfstep + koff),
                                         (AS3 void*)(&Bs[slot][dst1]), 16, 0, 0);
    };

    const int arow = lane & 15;
    const int xk0 = (((lane >> 4) << 4)) ^ (l7 << 4);
    const int xk1 = (64 + ((lane >> 4) << 4)) ^ (l7 << 4);
    auto ldf = [&](const unsigned short* slotbase, int rowbase, int xk) -> bf16x8 {
        return *(const bf16x8*)((const char*)slotbase + (rowbase + arow) * 128 + xk);
    };

    f32x4 acc[8][4] = {};

    stageA(0, 0); stageA(0, 1); stageB(0, 0); stageB(0, 1);
    asm volatile("s_waitcnt vmcnt(4)" ::: "memory");
    stageA(1, 0); stageB(1, 0); stageB(1, 1);
    asm volatile("s_waitcnt vmcnt(6)" ::: "memory");
    __builtin_amdgcn_s_barrier();

    bf16x8 af0[4][2], af1[4][2], bf0[2][2], bf1[2][2];

    for (int T = 0; T < nT; ++T) {
        const unsigned short* Aslot0 = As[(2 * T) & 3];
        const unsigned short* Aslot1 = As[(2 * T + 1) & 3];
        const unsigned short* Bslot0 = Bs[(2 * T) & 3];
        const unsigned short* Bslot1 = Bs[(2 * T + 1) & 3];

        // ---- phase 1: (ih0, jh0) ----
#pragma unroll
        for (int ii = 0; ii < 4; ++ii) {
            af0[ii][0] = ldf(Aslot0, ii * 32 + wm2 * 16, xk0);
            af0[ii][1] = ldf(Aslot0, ii * 32 + wm2 * 16, xk1);
        }
#pragma unroll
        for (int jj = 0; jj < 2; ++jj) {
            bf0[jj][0] = ldf(Bslot0, jj * 64 + wn4 * 16, xk0);
            bf0[jj][1] = ldf(Bslot0, jj * 64 + wn4 * 16, xk1);
        }
        stageA(T + 1, 1);
        __builtin_amdgcn_s_barrier();
        __builtin_amdgcn_s_setprio(1);
#pragma unroll
        for (int ii = 0; ii < 4; ++ii)
#pragma unroll
            for (int jj = 0; jj < 2; ++jj) {
                acc[ii][jj] = __builtin_amdgcn_mfma_f32_16x16x32_bf16(af0[ii][0], bf0[jj][0], acc[ii][jj], 0, 0, 0);
                acc[ii][jj] = __builtin_amdgcn_mfma_f32_16x16x32_bf16(af0[ii][1], bf0[jj][1], acc[ii][jj], 0, 0, 0);
            }
        __builtin_amdgcn_s_setprio(0);
        __builtin_amdgcn_s_barrier();

        // ---- phase 2: (ih0, jh1) ----
#pragma unroll
        for (int jj = 0; jj < 2; ++jj) {
            bf1[jj][0] = ldf(Bslot1, jj * 64 + wn4 * 16, xk0);
            bf1[jj][1] = ldf(Bslot1, jj * 64 + wn4 * 16, xk1);
        }
        stageA(T + 2, 0);
        __builtin_amdgcn_s_barrier();
        __builtin_amdgcn_s_setprio(1);
#pragma unroll
        for (int ii = 0; ii < 4; ++ii)
#pragma unroll
            for (int jj = 0; jj < 2; ++jj) {
                acc[ii][2 + jj] = __builtin_amdgcn_mfma_f32_16x16x32_bf16(af0[ii][0], bf1[jj][0], acc[ii][2 + jj], 0, 0, 0);
                acc[ii][2 + jj] = __builtin_amdgcn_mfma_f32_16x16x32_bf16(af0[ii][1], bf1[jj][1], acc[ii][2 + jj], 0, 0, 0);
            }
        __builtin_amdgcn_s_setprio(0);
        __builtin_amdgcn_s_barrier();

        // ---- phase 3: (ih1, jh0) ----
#pragma unroll
        for (int ii = 0; ii < 4; ++ii) {
            af1[ii][0] = ldf(Aslot1, ii * 32 + wm2 * 16, xk0);
            af1[ii][1] = ldf(Aslot1, ii * 32 + wm2 * 16, xk1);
        }
        stageB(T + 2, 0);
        __builtin_amdgcn_s_barrier();
        __builtin_amdgcn_s_setprio(1);
#pragma unroll
        for (int ii = 0; ii < 4; ++ii)
#pragma unroll
            for (int jj = 0; jj < 2; ++jj) {
                acc[4 + ii][jj] = __builtin_amdgcn_mfma_f32_16x16x32_bf16(af1[ii][0], bf0[jj][0], acc[4 + ii][jj], 0, 0, 0);
                acc[4 + ii][jj] = __builtin_amdgcn_mfma_f32_16x16x32_bf16(af1[ii][1], bf0[jj][1], acc[4 + ii][jj], 0, 0, 0);
            }
        __builtin_amdgcn_s_setprio(0);
        __builtin_amdgcn_s_barrier();

        // ---- phase 4: (ih1, jh1); gate for tile T+1 ----
        stageB(T + 2, 1);
        if (T + 3 <= nT) {
            asm volatile("s_waitcnt vmcnt(6)" ::: "memory");
        } else {
            asm volatile("s_waitcnt vmcnt(0)" ::: "memory");
        }
        __builtin_amdgcn_s_barrier();
        __builtin_amdgcn_s_setprio(1);
#pragma unroll
        for (int ii = 0; ii < 4; ++ii)
#pragma unroll
            for (int jj = 0; jj < 2; ++jj) {
                acc[4 + ii][2 + jj] = __builtin_amdgcn_mfma_f32_16x16x32_bf16(af1[ii][0], bf1[jj][0], acc[4 + ii][2 + jj], 0, 0, 0);
                acc[4 + ii][2 + jj] = __builtin_amdgcn_mfma_f32_16x16x32_bf16(af1[ii][1], bf1[jj][1], acc[4 + ii][2 + jj], 0, 0, 0);
            }
        __builtin_amdgcn_s_setprio(0);
        __builtin_amdgcn_s_barrier();
    }

    // ---------- epilogue: C-tile through LDS, coalesced dwordx4 stores ----------
    // C/D frag layout: col=lane&15, row=(lane>>4)*4+r  [m89]
    const int cn = lane & 15;
    const int rbase = (lane >> 4) * 4;
    __syncthreads();   // all staging drained (vmcnt0 at last gate) + all ds_reads done

    if (GELU_BF16_OUT) {
        // 256x256 bf16 tile = 128 KB, exactly the smem. byte = row*512 + col*2, swz ^((row&7)<<4)
#pragma unroll
        for (int i = 0; i < 8; ++i) {
            int lr = (i >> 2) * 128 + (i & 3) * 32 + wm2 * 16 + rbase;
#pragma unroll
            for (int j = 0; j < 4; ++j) {
                int nl = (j >> 1) * 128 + (j & 1) * 64 + wn4 * 16 + cn;
                float bv = bias[n0 + nl];
#pragma unroll
                for (int r = 0; r < 4; ++r) {
                    float c = gelu_fast(acc[i][j][r] + bv);
                    int row = lr + r;
                    int byte = (row << 9) + (nl << 1);
                    byte ^= (row & 7) << 4;
                    *(unsigned short*)((char*)smem + byte) = f2bf(c);
                }
            }
        }
        __syncthreads();
#pragma unroll
        for (int u = 0; u < 16; ++u) {
            int off = u * 8192 + tid * 16;
            int row = off >> 9, colb = off & 511;
            int src = off ^ ((row & 7) << 4);
            *(int4*)((char*)Cout + ((size_t)(m0 + row) * N + n0) * 2 + colb) =
                *(const int4*)((const char*)smem + src);
        }
    } else {
        // f32 out: two 128-row passes of 128x256 f32 = 128 KB. byte = row*1024 + col*4
        float* smf = (float*)smem;
#pragma unroll
        for (int p = 0; p < 2; ++p) {
            if (p) __syncthreads();
#pragma unroll
            for (int ii = 0; ii < 4; ++ii) {
                int i = p * 4 + ii;
                int lr = (i & 3) * 32 + wm2 * 16 + rbase;   // local row within 128-row half
#pragma unroll
                for (int j = 0; j < 4; ++j) {
                    int nl = (j >> 1) * 128 + (j & 1) * 64 + wn4 * 16 + cn;
                    float bv = bias[n0 + nl];
#pragma unroll
                    for (int r = 0; r < 4; ++r) {
                        int row = lr + r;
                        int byte = (row << 10) + (nl << 2);
                        byte ^= (row & 7) << 4;
                        *(float*)((char*)smf + byte) = acc[p * 4 + ii][j][r] + bv;
                    }
                }
            }
            __syncthreads();
#pragma unroll
            for (int u = 0; u < 16; ++u) {
                int off = u * 8192 + tid * 16;
                int row = off >> 10, colb = off & 1023;
                int src = off ^ ((row & 7) << 4);
                *(int4*)((char*)Cout + ((size_t)(m0 + p * 128 + row) * N + n0) * 4 + colb) =
                    *(const int4*)((const char*)smf + src);
            }
        }
    }
}

// per-row LayerNorm in place, float4. grid rows, block 256
__global__ void ln_rows_kernel(float* __restrict__ x, const float* __restrict__ g,
                               const float* __restrict__ beta) {
    __shared__ float red[32];
    float* p = x + (size_t)blockIdx.x * H;
    int t = threadIdx.x;
    float4 v = *(const float4*)(p + t * 4);
    float s = v.x + v.y + v.z + v.w;
    float mu = block_sum(s, red) * (1.0f / H);
    float4 d = { v.x - mu, v.y - mu, v.z - mu, v.w - mu };
    float d2 = d.x * d.x + d.y * d.y + d.z * d.z + d.w * d.w;
    float var = block_sum(d2, red) * (1.0f / H);
    float inv = rsqrtf(var + LN_EPS);
    float4 gg = *(const float4*)(g + t * 4);
    float4 bb = *(const float4*)(beta + t * 4);
    float4 o = { d.x * inv * gg.x + bb.x, d.y * inv * gg.y + bb.y,
                 d.z * inv * gg.z + bb.z, d.w * inv * gg.w + bb.w };
    *(float4*)(p + t * 4) = o;
}

// ---------- launch ----------

extern "C" void kernel_launch(void* const* d_in, const int* in_sizes, int n_in,
                              void* d_out, int out_size, void* d_ws, size_t ws_size,
                              hipStream_t stream) {
    const float* hs     = (const float*)d_in[0];
    const float* ent    = (const float*)d_in[1];
    const float* ee_w1  = (const float*)d_in[2];
    const float* ee_b1  = (const float*)d_in[3];
    const float* ee_w2  = (const float*)d_in[4];
    const float* ee_b2  = (const float*)d_in[5];
    const float* ee_g   = (const float*)d_in[6];
    const float* ee_be  = (const float*)d_in[7];
    const float* re_w1  = (const float*)d_in[8];
    const float* re_b1  = (const float*)d_in[9];
    const float* re_w2  = (const float*)d_in[10];
    const float* re_b2  = (const float*)d_in[11];
    const float* re_g   = (const float*)d_in[12];
    const float* re_be  = (const float*)d_in[13];
    const float* rn_w1  = (const float*)d_in[14];
    const float* rn_b1  = (const float*)d_in[15];
    const float* rn_w2  = (const float*)d_in[16];
    const float* rn_b2  = (const float*)d_in[17];
    const float* rn_g   = (const float*)d_in[18];
    const float* rn_be  = (const float*)d_in[19];
    const float* vn_w1  = (const float*)d_in[20];
    const float* vn_b1  = (const float*)d_in[21];
    const float* vn_w2  = (const float*)d_in[22];
    const float* vn_b2  = (const float*)d_in[23];

    float* out = (float*)d_out;
    float* ef   = out;
    float* rel  = ef + (size_t)BATCH * SEQ * H;
    float* retr = rel + BATCH * H;
    float* sims = retr + BATCH * TOPK * H;
    float* tidx = sims + BATCH * N_ENT;
    float* ro   = tidx + BATCH * TOPK;
    float* vs   = ro + BATCH * H;

    float* ws = (float*)d_ws;
    size_t o = 0;
    float* pooled = ws + o; o += 8192;
    int*   idx_i  = (int*)(ws + o); o += 64;
    float* xin    = ws + o; o += 8 * 3 * H;
    float* partA  = ws + o; o += 48 * 8 * 2048;   // 786432 fl; also holds pool partials (256K)
    float* partB  = ws + o; o += 32 * 8 * 1024;   // 262144 fl
    unsigned short* w1t = (unsigned short*)(ws + o); o += (2048 * 1024) / 2;
    unsigned short* w2t = (unsigned short*)(ws + o); o += (2048 * 1024) / 2;
    unsigned short* hsb = (unsigned short*)(ws + o);

    long long avail = (long long)(ws_size / 4) - (long long)o;
    int chunk = (int)(avail / 1536);  // per row: 512 (hsb) + 1024 (mid) floats
    chunk &= ~255;                    // 256-row tiles
    int total = BATCH * SEQ;
    if (chunk > total) chunk = total;
    if (chunk < 256) chunk = 256;
    bool full = (chunk >= total);
    unsigned short* midb = hsb + (size_t)chunk * H;

    // pooling phase 1 (+ hs->bf16 fused when ws fits all rows); partials into partA
    pool1_kernel<<<dim3(32, BATCH), 256, 0, stream>>>(hs, partA, full ? hsb : nullptr);

    // weight prep (both transposes, one launch)
    transpose_both_kernel<<<4096, 256, 0, stream>>>(ee_w1, w1t, ee_w2, w2t);

    // pooling phase 2
    pool2_kernel<<<BATCH, 256, 0, stream>>>(partA, pooled);

    // relation encoder: partial -> fused(reduce+gelu)+partial -> LN
    mlp_partial_kernel<32><<<dim3(4, 32), 256, 0, stream>>>(pooled, H, re_w1, H, partA);
    mlp_partial_fused_kernel<32><<<dim3(4, 32), 256, 0, stream>>>(partA, H, 32, re_b1,
                                                                  re_w2, H, partB);
    mlp_reduce_ln_kernel<<<BATCH, 1024, 0, stream>>>(partB, re_b2, re_g, re_be, rel, 32);

    sim_kernel<<<250, 256, 0, stream>>>(rel, ent, sims);
    topk_kernel<<<BATCH, 256, 0, stream>>>(sims, tidx, idx_i);
    gather_concat_kernel<<<BATCH, 1024, 0, stream>>>(ent, idx_i, rel, pooled, retr, xin);

    // reasoning network
    mlp_partial_kernel<64><<<dim3(8, 48), 256, 0, stream>>>(xin, 3 * H, rn_w1, 2 * H, partA);
    mlp_partial_fused_kernel<64><<<dim3(4, 32), 256, 0, stream>>>(partA, 2 * H, 48, rn_b1,
                                                                  rn_w2, H, partB);
    mlp_reduce_ln_kernel<<<BATCH, 1024, 0, stream>>>(partB, rn_b2, rn_g, rn_be, ro, 32);

    // validation network
    mlp_partial_kernel<64><<<dim3(2, 16), 256, 0, stream>>>(ro, H, vn_w1, 512, partA);
    vn_final_kernel<<<BATCH, 512, 0, stream>>>(partA, vn_b1, vn_w2, vn_b2, vs, 16);

    // entity encoder (bf16 MFMA, 256^2 pipeline)
    for (int r0 = 0; r0 < total; r0 += chunk) {
        int m = total - r0;
        if (m > chunk) m = chunk;
        if (!full) {
            int nconv = m * H;
            f2bf_kernel<<<(nconv / 4 + 255) / 256, 256, 0, stream>>>(hs + (size_t)r0 * H, hsb, nconv);
        }
        unsigned short* a1 = full ? (hsb + (size_t)r0 * H) : hsb;
        gemm256_8ph<1><<<(m / 256) * (2048 / 256), 512, 0, stream>>>(a1, w1t, ee_b1, midb,
                                                                     m, 2048, 1024);
        gemm256_8ph<0><<<(m / 256) * (1024 / 256), 512, 0, stream>>>(midb, w2t, ee_b2,
                                                                     ef + (size_t)r0 * H,
                                                                     m, 1024, 2048);
    }
    ln_rows_kernel<<<total, 256, 0, stream>>>(ef, ee_g, ee_be);
}

// Round 5
// 498.157 us; speedup vs baseline: 1.3292x; 1.0730x over previous
//
#include <hip/hip_runtime.h>
#include <math.h>

#define H 1024
#define SEQ 2048
#define BATCH 8
#define N_ENT 1000
#define TOPK 5
#define LN_EPS 1e-5f

using bf16x8 = __attribute__((ext_vector_type(8))) __bf16;
using f32x4  = __attribute__((ext_vector_type(4))) float;
#define AS1 __attribute__((address_space(1)))
#define AS3 __attribute__((address_space(3)))

// ---------- helpers ----------

// fast erf-GELU: Abramowitz-Stegun 7.1.26, |erf err| <= 1.5e-7, hw rcp/exp2
__device__ __forceinline__ float gelu_fast(float x) {
    float z = fabsf(x) * 0.70710678118654752440f;
    float t = __builtin_amdgcn_rcpf(fmaf(0.3275911f, z, 1.0f));
    float p = fmaf(fmaf(fmaf(fmaf(1.061405429f, t, -1.453152027f), t, 1.421413741f),
                        t, -0.284496736f), t, 0.254829592f) * t;
    float e = __builtin_amdgcn_exp2f(-z * z * 1.44269504088896f);
    float erfz = fmaf(-p, e, 1.0f);
    float s = copysignf(erfz, x);
    return 0.5f * x * (1.0f + s);
}

__device__ __forceinline__ float sigmoidf_(float x) {
    return 1.0f / (1.0f + expf(-x));
}

__device__ __forceinline__ unsigned short f2bf(float f) {
    unsigned int u = __float_as_uint(f);
    unsigned int r = (u + 0x7fffu + ((u >> 16) & 1u)) >> 16;  // RNE
    return (unsigned short)r;
}

__device__ float block_sum(float v, float* red) {
    for (int off = 32; off > 0; off >>= 1) v += __shfl_down(v, off, 64);
    int wid = threadIdx.x >> 6;
    int lane = threadIdx.x & 63;
    int nw = blockDim.x >> 6;
    if (lane == 0) red[wid] = v;
    __syncthreads();
    if (threadIdx.x == 0) {
        float s = 0.f;
        for (int i = 0; i < nw; ++i) s += red[i];
        red[0] = s;
    }
    __syncthreads();
    float r = red[0];
    __syncthreads();
    return r;
}

// ---------- conversion kernels ----------

__global__ void f2bf_kernel(const float* __restrict__ in, unsigned short* __restrict__ out, int n) {
    int i = (blockIdx.x * blockDim.x + threadIdx.x) * 4;
    if (i >= n) return;
    float4 v = *(const float4*)(in + i);
    ushort4 o;
    o.x = f2bf(v.x); o.y = f2bf(v.y); o.z = f2bf(v.z); o.w = f2bf(v.w);
    *(ushort4*)(out + i) = o;
}

// both weight transposes in one launch. bid<2048: ee_w1 (1024x2048); else ee_w2 (2048x1024)
__global__ void transpose_both_kernel(const float* __restrict__ w1, unsigned short* __restrict__ o1,
                                      const float* __restrict__ w2, unsigned short* __restrict__ o2) {
    __shared__ float tile[32][33];
    int bid = blockIdx.x;
    const float* in; unsigned short* out; int R, C, bx, by;
    if (bid < 2048) { in = w1; out = o1; R = 1024; C = 2048; bx = bid & 63; by = bid >> 6; }
    else { bid -= 2048; in = w2; out = o2; R = 2048; C = 1024; bx = bid & 31; by = bid >> 5; }
    int c0 = bx * 32, r0 = by * 32;
    int tx = threadIdx.x & 31, ty = threadIdx.x >> 5;
#pragma unroll
    for (int i = 0; i < 32; i += 8)
        tile[ty + i][tx] = in[(size_t)(r0 + ty + i) * C + c0 + tx];
    __syncthreads();
#pragma unroll
    for (int i = 0; i < 32; i += 8)
        out[(size_t)(c0 + ty + i) * R + r0 + tx] = f2bf(tile[tx][ty + i]);
}

// ---------- pooling (2-phase) + fused hs->bf16 ----------

// grid (64, 8), block 256; 32 rows per block (2 blocks/CU for TLP)
__global__ void pool1_kernel(const float* __restrict__ hs, float* __restrict__ part,
                             unsigned short* __restrict__ hsb) {
    int sc = blockIdx.x, b = blockIdx.y, t = threadIdx.x;
    size_t rowbase = (size_t)b * SEQ + sc * 32;
    const float* p = hs + rowbase * H + t * 4;
    float4 a = {0.f, 0.f, 0.f, 0.f};
    if (hsb) {
#pragma unroll 4
        for (int s = 0; s < 32; ++s) {
            float4 v = *(const float4*)(p + (size_t)s * H);
            a.x += v.x; a.y += v.y; a.z += v.z; a.w += v.w;
            ushort4 o;
            o.x = f2bf(v.x); o.y = f2bf(v.y); o.z = f2bf(v.z); o.w = f2bf(v.w);
            *(ushort4*)(hsb + (rowbase + s) * H + t * 4) = o;
        }
    } else {
#pragma unroll 4
        for (int s = 0; s < 32; ++s) {
            float4 v = *(const float4*)(p + (size_t)s * H);
            a.x += v.x; a.y += v.y; a.z += v.z; a.w += v.w;
        }
    }
    *(float4*)(part + ((size_t)b * 64 + sc) * H + t * 4) = a;
}

// grid 8, block 256; float4 cols per thread
__global__ void pool2_kernel(const float* __restrict__ part, float* __restrict__ pooled) {
    int b = blockIdx.x, t = threadIdx.x;
    float4 s = {0.f, 0.f, 0.f, 0.f};
    for (int sc = 0; sc < 64; ++sc) {
        float4 v = *(const float4*)(part + ((size_t)b * 64 + sc) * H + t * 4);
        s.x += v.x; s.y += v.y; s.z += v.z; s.w += v.w;
    }
    float4 o = {s.x * (1.0f / SEQ), s.y * (1.0f / SEQ), s.z * (1.0f / SEQ), s.w * (1.0f / SEQ)};
    *(float4*)(pooled + (size_t)b * H + t * 4) = o;
}

// ---------- small MLP path: k-split partial + fused-reduce partial ----------

// partial[ks][b][j] = sum_{k in ks-range} X[b][k] * W[k][j]
template <int KRANGE>
__global__ void mlp_partial_kernel(const float* __restrict__ X, int ldx,
                                   const float* __restrict__ W, int N,
                                   float* __restrict__ part) {
    __shared__ float xs[8][KRANGE];
    int jb = blockIdx.x, ks = blockIdx.y, t = threadIdx.x;
    int k0 = ks * KRANGE;
    for (int i = t; i < 8 * KRANGE; i += 256) {
        int b = i / KRANGE, k = i % KRANGE;
        xs[b][k] = X[(size_t)b * ldx + k0 + k];
    }
    __syncthreads();
    int j = jb * 256 + t;
    float acc[8] = {};
    for (int k = 0; k < KRANGE; ++k) {
        float w = W[(size_t)(k0 + k) * N + j];
#pragma unroll
        for (int b = 0; b < 8; ++b) acc[b] = fmaf(xs[b][k], w, acc[b]);
    }
#pragma unroll
    for (int b = 0; b < 8; ++b) part[((size_t)(ks * 8 + b)) * N + j] = acc[b];
}

// same, but X = gelu(b1 + sum_q Pprev[q][b][col]) computed on the fly (fused reduce+gelu)
template <int KRANGE>
__global__ void mlp_partial_fused_kernel(const float* __restrict__ Pprev, int ldp, int nksp,
                                         const float* __restrict__ b1,
                                         const float* __restrict__ W, int N,
                                         float* __restrict__ part) {
    __shared__ float xs[8][KRANGE];
    int jb = blockIdx.x, ks = blockIdx.y, t = threadIdx.x;
    int k0 = ks * KRANGE;
    for (int i = t; i < 8 * KRANGE; i += 256) {
        int b = i / KRANGE, k = i % KRANGE;
        int col = k0 + k;
        float s = b1[col];
        for (int q = 0; q < nksp; ++q) s += Pprev[((size_t)(q * 8 + b)) * ldp + col];
        xs[b][k] = gelu_fast(s);
    }
    __syncthreads();
    int j = jb * 256 + t;
    float acc[8] = {};
    for (int k = 0; k < KRANGE; ++k) {
        float w = W[(size_t)(k0 + k) * N + j];
#pragma unroll
        for (int b = 0; b < 8; ++b) acc[b] = fmaf(xs[b][k], w, acc[b]);
    }
#pragma unroll
    for (int b = 0; b < 8; ++b) part[((size_t)(ks * 8 + b)) * N + j] = acc[b];
}

__global__ void mlp_reduce_ln_kernel(const float* __restrict__ part, const float* __restrict__ bias,
                                     const float* __restrict__ g, const float* __restrict__ be,
                                     float* __restrict__ out, int nks) {
    __shared__ float red[32];
    int b = blockIdx.x, t = threadIdx.x;
    float s = bias[t];
    for (int ks = 0; ks < nks; ++ks) s += part[((size_t)(ks * 8 + b)) * H + t];
    float mu = block_sum(s, red) * (1.0f / H);
    float d = s - mu;
    float var = block_sum(d * d, red) * (1.0f / H);
    out[(size_t)b * H + t] = d * rsqrtf(var + LN_EPS) * g[t] + be[t];
}

// ---------- sims / topk / gather+concat / validation tail ----------

__global__ void sim_kernel(const float* __restrict__ rel, const float* __restrict__ ent,
                           float* __restrict__ sims) {
    __shared__ float rl[8 * H];
    int t = threadIdx.x;
    for (int i = t; i < 8 * H; i += 256) rl[i] = rel[i];
    __syncthreads();
    int e = blockIdx.x * 4 + (t >> 6);
    int lane = t & 63;
    float ev[16];
    const float* ep = ent + (size_t)e * H;
#pragma unroll
    for (int i = 0; i < 16; ++i) ev[i] = ep[lane + i * 64];
#pragma unroll
    for (int b = 0; b < 8; ++b) {
        float a = 0.f;
#pragma unroll
        for (int i = 0; i < 16; ++i) a = fmaf(ev[i], rl[b * H + lane + i * 64], a);
        for (int off = 32; off > 0; off >>= 1) a += __shfl_down(a, off, 64);
        if (lane == 0) sims[b * N_ENT + e] = a;
    }
}

__global__ void topk_kernel(const float* __restrict__ sims, float* __restrict__ out_idx_f,
                            int* __restrict__ idx_i) {
    __shared__ float v[1024];
    __shared__ float rv[4];
    __shared__ int ri[4];
    int b = blockIdx.x, t = threadIdx.x;
    for (int i = t; i < 1024; i += 256) v[i] = (i < N_ENT) ? sims[b * N_ENT + i] : -INFINITY;
    __syncthreads();
    for (int k = 0; k < TOPK; ++k) {
        float best = -INFINITY;
        int bi = 0x7fffffff;
        for (int i = t; i < 1024; i += 256) {
            float x = v[i];
            if (x > best || (x == best && i < bi)) { best = x; bi = i; }
        }
        for (int off = 32; off > 0; off >>= 1) {
            float ov = __shfl_down(best, off, 64);
            int oi = __shfl_down(bi, off, 64);
            if (ov > best || (ov == best && oi < bi)) { best = ov; bi = oi; }
        }
        if ((t & 63) == 0) { rv[t >> 6] = best; ri[t >> 6] = bi; }
        __syncthreads();
        if (t == 0) {
            for (int w = 1; w < 4; ++w)
                if (rv[w] > rv[0] || (rv[w] == rv[0] && ri[w] < ri[0])) { rv[0] = rv[w]; ri[0] = ri[w]; }
            int sel = ri[0];
            out_idx_f[b * TOPK + k] = (float)sel;
            idx_i[b * TOPK + k] = sel;
            v[sel] = -INFINITY;
        }
        __syncthreads();
    }
}

__global__ void gather_concat_kernel(const float* __restrict__ ent, const int* __restrict__ idx,
                                     const float* __restrict__ rel, const float* __restrict__ pooled,
                                     float* __restrict__ retrieved, float* __restrict__ xin) {
    int b = blockIdx.x, h = threadIdx.x;
    float acc = 0.f;
    for (int k = 0; k < TOPK; ++k) {
        float v = ent[(size_t)idx[b * TOPK + k] * H + h];
        retrieved[((size_t)b * TOPK + k) * H + h] = v;
        acc += v;
    }
    float* xb = xin + (size_t)b * 3 * H;
    xb[h] = acc * (1.0f / TOPK);
    xb[H + h] = rel[b * H + h];
    xb[2 * H + h] = pooled[b * H + h];
}

// partial sums of vn layer1 in, gelu+dot+sigmoid.  grid 8, block 512
__global__ void vn_final_kernel(const float* __restrict__ part, const float* __restrict__ b1,
                                const float* __restrict__ w2, const float* __restrict__ b2,
                                float* __restrict__ vs, int nks) {
    __shared__ float red[32];
    int b = blockIdx.x, t = threadIdx.x;
    float s = b1[t];
    for (int ks = 0; ks < nks; ++ks) s += part[((size_t)(ks * 8 + b)) * 512 + t];
    float c = gelu_fast(s) * w2[t];
    float tot = block_sum(c, red);
    if (t == 0) vs[b] = sigmoidf_(tot + b2[0]);
}

// ---------- bf16 MFMA GEMM: 256x256 tile, BK=64, 8 waves, 4-phase schedule ----------
// DEEPENED counted-vmcnt pipeline: per-phase gates vmcnt(10) (5 stage-calls / 10 loads
// in flight; prefetch horizon 5 stage-intervals vs 3 before), placed before the
// closing barrier of p4/p1/p2 so loads stay in flight across MFMA clusters.
// In-order vmcnt retirement => "all but newest N loads retired"; slot ring of 4
// half-slots per operand; each stage's target slot was last ds_read >=1 barrier
// before stage issue. Tail tiles: skipped stages shrink the after-count, so
// p4-end uses vmcnt(0) when T+2>=nT and p2-end uses vmcnt(8) then.
// Direct-store epilogue (R1 version; LDS-staged variant measured slower).
template <int GELU_BF16_OUT>
__global__ __launch_bounds__(512, 2) void gemm256_8ph(const unsigned short* __restrict__ A,
                                                      const unsigned short* __restrict__ Bt,
                                                      const float* __restrict__ bias,
                                                      void* __restrict__ Cout,
                                                      int M, int N, int K) {
    __shared__ __align__(16) unsigned short As[4][128 * 64];
    __shared__ __align__(16) unsigned short Bs[4][128 * 64];
    const int tid = threadIdx.x;
    const int lane = tid & 63;
    const int w = tid >> 6;
    const int wm2 = w >> 2;   // 0..1
    const int wn4 = w & 3;    // 0..3

    const int Np = N >> 8;
    const int nwg = gridDim.x;
    int bid = blockIdx.x;
    int s = bid;
    if ((nwg & 7) == 0) s = (bid & 7) * (nwg >> 3) + (bid >> 3);  // XCD-chunked, bijective
    const int m0 = (s / Np) << 8;
    const int n0 = (s % Np) << 8;

    const int nT = K >> 6;

    const int l7 = lane & 7;
    const int lrow0 = w * 16 + (lane >> 3);
    const int lrow1 = lrow0 + 8;
    const int kel0 = ((l7 ^ (lrow0 & 7)) << 3);   // pre-swizzled k element offset
    const int kel1 = ((l7 ^ (lrow1 & 7)) << 3);
    const unsigned short* pa0 = A + (size_t)(m0 + lrow0) * K + kel0;
    const unsigned short* pa1 = A + (size_t)(m0 + lrow1) * K + kel1;
    const unsigned short* pb0 = Bt + (size_t)(n0 + lrow0) * K + kel0;
    const unsigned short* pb1 = Bt + (size_t)(n0 + lrow1) * K + kel1;
    const size_t halfstep = (size_t)128 * K;
    const int dst0 = (w * 16) * 64;
    const int dst1 = dst0 + 8 * 64;

    auto stageA = [&](int t, int half) {
        if (t >= nT) return;
        int slot = (2 * t + half) & 3;
        int koff = t << 6;
        __builtin_amdgcn_global_load_lds((AS1 void*)(pa0 + half * halfstep + koff),
                                         (AS3 void*)(&As[slot][dst0]), 16, 0, 0);
        __builtin_amdgcn_global_load_lds((AS1 void*)(pa1 + half * halfstep + koff),
                                         (AS3 void*)(&As[slot][dst1]), 16, 0, 0);
    };
    auto stageB = [&](int t, int half) {
        if (t >= nT) return;
        int slot = (2 * t + half) & 3;
        int koff = t << 6;
        __builtin_amdgcn_global_load_lds((AS1 void*)(pb0 + half * halfstep + koff),
                                         (AS3 void*)(&Bs[slot][dst0]), 16, 0, 0);
        __builtin_amdgcn_global_load_lds((AS1 void*)(pb1 + half * halfstep + koff),
                                         (AS3 void*)(&Bs[slot][dst1]), 16, 0, 0);
    };

    const int arow = lane & 15;
    const int xk0 = (((lane >> 4) << 4)) ^ (l7 << 4);
    const int xk1 = (64 + ((lane >> 4) << 4)) ^ (l7 << 4);
    auto ldf = [&](const unsigned short* slotbase, int rowbase, int xk) -> bf16x8 {
        return *(const bf16x8*)((const char*)slotbase + (rowbase + arow) * 128 + xk);
    };

    f32x4 acc[8][4] = {};

    // ---- prologue: stages 1..7 = A0(0),B0(0),A1(0),B1(0),A0(1),B0(1),B1(1) ----
    stageA(0, 0); stageB(0, 0); stageA(0, 1); stageB(0, 1);
    stageA(1, 0); stageB(1, 0); stageB(1, 1);
    asm volatile("s_waitcnt vmcnt(10)" ::: "memory");   // oldest 2 stages (A0(0),B0(0)) retired
    __builtin_amdgcn_s_barrier();

    bf16x8 af0[4][2], af1[4][2], bf0[2][2], bf1[2][2];

    for (int T = 0; T < nT; ++T) {
        const unsigned short* Aslot0 = As[(2 * T) & 3];
        const unsigned short* Aslot1 = As[(2 * T + 1) & 3];
        const unsigned short* Bslot0 = Bs[(2 * T) & 3];
        const unsigned short* Bslot1 = Bs[(2 * T + 1) & 3];

        // ---- phase 1: (ih0, jh0); reads A0(T),B0(T) ----
#pragma unroll
        for (int ii = 0; ii < 4; ++ii) {
            af0[ii][0] = ldf(Aslot0, ii * 32 + wm2 * 16, xk0);
            af0[ii][1] = ldf(Aslot0, ii * 32 + wm2 * 16, xk1);
        }
#pragma unroll
        for (int jj = 0; jj < 2; ++jj) {
            bf0[jj][0] = ldf(Bslot0, jj * 64 + wn4 * 16, xk0);
            bf0[jj][1] = ldf(Bslot0, jj * 64 + wn4 * 16, xk1);
        }
        stageA(T + 1, 1);
        __builtin_amdgcn_s_barrier();
        __builtin_amdgcn_s_setprio(1);
#pragma unroll
        for (int ii = 0; ii < 4; ++ii)
#pragma unroll
            for (int jj = 0; jj < 2; ++jj) {
                acc[ii][jj] = __builtin_amdgcn_mfma_f32_16x16x32_bf16(af0[ii][0], bf0[jj][0], acc[ii][jj], 0, 0, 0);
                acc[ii][jj] = __builtin_amdgcn_mfma_f32_16x16x32_bf16(af0[ii][1], bf0[jj][1], acc[ii][jj], 0, 0, 0);
            }
        __builtin_amdgcn_s_setprio(0);
        // gate for p2's B1(T): T==0 -> only 4 stages after it, else 5
        if (T == 0) asm volatile("s_waitcnt vmcnt(8)" ::: "memory");
        else        asm volatile("s_waitcnt vmcnt(10)" ::: "memory");
        __builtin_amdgcn_s_barrier();

        // ---- phase 2: (ih0, jh1); reads B1(T) ----
#pragma unroll
        for (int jj = 0; jj < 2; ++jj) {
            bf1[jj][0] = ldf(Bslot1, jj * 64 + wn4 * 16, xk0);
            bf1[jj][1] = ldf(Bslot1, jj * 64 + wn4 * 16, xk1);
        }
        stageA(T + 2, 0);
        __builtin_amdgcn_s_barrier();
        __builtin_amdgcn_s_setprio(1);
#pragma unroll
        for (int ii = 0; ii < 4; ++ii)
#pragma unroll
            for (int jj = 0; jj < 2; ++jj) {
                acc[ii][2 + jj] = __builtin_amdgcn_mfma_f32_16x16x32_bf16(af0[ii][0], bf1[jj][0], acc[ii][2 + jj], 0, 0, 0);
                acc[ii][2 + jj] = __builtin_amdgcn_mfma_f32_16x16x32_bf16(af0[ii][1], bf1[jj][1], acc[ii][2 + jj], 0, 0, 0);
            }
        __builtin_amdgcn_s_setprio(0);
        // gate for p3's A1(T): the p2 stage (A0(T+2)) is skipped when T+2>=nT
        if (T + 2 >= nT) asm volatile("s_waitcnt vmcnt(8)" ::: "memory");
        else             asm volatile("s_waitcnt vmcnt(10)" ::: "memory");
        __builtin_amdgcn_s_barrier();

        // ---- phase 3: (ih1, jh0); reads A1(T) ----
#pragma unroll
        for (int ii = 0; ii < 4; ++ii) {
            af1[ii][0] = ldf(Aslot1, ii * 32 + wm2 * 16, xk0);
            af1[ii][1] = ldf(Aslot1, ii * 32 + wm2 * 16, xk1);
        }
        stageB(T + 2, 0);
        __builtin_amdgcn_s_barrier();
        __builtin_amdgcn_s_setprio(1);
#pragma unroll
        for (int ii = 0; ii < 4; ++ii)
#pragma unroll
            for (int jj = 0; jj < 2; ++jj) {
                acc[4 + ii][jj] = __builtin_amdgcn_mfma_f32_16x16x32_bf16(af1[ii][0], bf0[jj][0], acc[4 + ii][jj], 0, 0, 0);
                acc[4 + ii][jj] = __builtin_amdgcn_mfma_f32_16x16x32_bf16(af1[ii][1], bf0[jj][1], acc[4 + ii][jj], 0, 0, 0);
            }
        __builtin_amdgcn_s_setprio(0);
        __builtin_amdgcn_s_barrier();

        // ---- phase 4: (ih1, jh1); no reads ----
        stageB(T + 2, 1);
        __builtin_amdgcn_s_barrier();
        __builtin_amdgcn_s_setprio(1);
#pragma unroll
        for (int ii = 0; ii < 4; ++ii)
#pragma unroll
            for (int jj = 0; jj < 2; ++jj) {
                acc[4 + ii][2 + jj] = __builtin_amdgcn_mfma_f32_16x16x32_bf16(af1[ii][0], bf1[jj][0], acc[4 + ii][2 + jj], 0, 0, 0);
                acc[4 + ii][2 + jj] = __builtin_amdgcn_mfma_f32_16x16x32_bf16(af1[ii][1], bf1[jj][1], acc[4 + ii][2 + jj], 0, 0, 0);
            }
        __builtin_amdgcn_s_setprio(0);
        // gate for next tile's p1 (A0(T+1),B0(T+1)); drain when later stages skipped
        if (T + 2 < nT) asm volatile("s_waitcnt vmcnt(10)" ::: "memory");
        else            asm volatile("s_waitcnt vmcnt(0)" ::: "memory");
        __builtin_amdgcn_s_barrier();
    }

    // C/D layout: col=lane&15, row=(lane>>4)*4+r  [m89]
    const int cn = lane & 15;
    const int rbase = (lane >> 4) * 4;
#pragma unroll
    for (int i = 0; i < 8; ++i) {
        int mbase = m0 + (i >> 2) * 128 + (i & 3) * 32 + wm2 * 16 + rbase;
#pragma unroll
        for (int j = 0; j < 4; ++j) {
            int n = n0 + (j >> 1) * 128 + (j & 1) * 64 + wn4 * 16 + cn;
            float bv = bias[n];
#pragma unroll
            for (int r = 0; r < 4; ++r) {
                float c = acc[i][j][r] + bv;
                if (GELU_BF16_OUT) {
                    c = gelu_fast(c);
                    ((unsigned short*)Cout)[(size_t)(mbase + r) * N + n] = f2bf(c);
                } else {
                    ((float*)Cout)[(size_t)(mbase + r) * N + n] = c;
                }
            }
        }
    }
}

// per-row LayerNorm in place, float4. grid rows, block 256
__global__ void ln_rows_kernel(float* __restrict__ x, const float* __restrict__ g,
                               const float* __restrict__ beta) {
    __shared__ float red[32];
    float* p = x + (size_t)blockIdx.x * H;
    int t = threadIdx.x;
    float4 v = *(const float4*)(p + t * 4);
    float s = v.x + v.y + v.z + v.w;
    float mu = block_sum(s, red) * (1.0f / H);
    float4 d = { v.x - mu, v.y - mu, v.z - mu, v.w - mu };
    float d2 = d.x * d.x + d.y * d.y + d.z * d.z + d.w * d.w;
    float var = block_sum(d2, red) * (1.0f / H);
    float inv = rsqrtf(var + LN_EPS);
    float4 gg = *(const float4*)(g + t * 4);
    float4 bb = *(const float4*)(beta + t * 4);
    float4 o = { d.x * inv * gg.x + bb.x, d.y * inv * gg.y + bb.y,
                 d.z * inv * gg.z + bb.z, d.w * inv * gg.w + bb.w };
    *(float4*)(p + t * 4) = o;
}

// ---------- launch ----------

extern "C" void kernel_launch(void* const* d_in, const int* in_sizes, int n_in,
                              void* d_out, int out_size, void* d_ws, size_t ws_size,
                              hipStream_t stream) {
    const float* hs     = (const float*)d_in[0];
    const float* ent    = (const float*)d_in[1];
    const float* ee_w1  = (const float*)d_in[2];
    const float* ee_b1  = (const float*)d_in[3];
    const float* ee_w2  = (const float*)d_in[4];
    const float* ee_b2  = (const float*)d_in[5];
    const float* ee_g   = (const float*)d_in[6];
    const float* ee_be  = (const float*)d_in[7];
    const float* re_w1  = (const float*)d_in[8];
    const float* re_b1  = (const float*)d_in[9];
    const float* re_w2  = (const float*)d_in[10];
    const float* re_b2  = (const float*)d_in[11];
    const float* re_g   = (const float*)d_in[12];
    const float* re_be  = (const float*)d_in[13];
    const float* rn_w1  = (const float*)d_in[14];
    const float* rn_b1  = (const float*)d_in[15];
    const float* rn_w2  = (const float*)d_in[16];
    const float* rn_b2  = (const float*)d_in[17];
    const float* rn_g   = (const float*)d_in[18];
    const float* rn_be  = (const float*)d_in[19];
    const float* vn_w1  = (const float*)d_in[20];
    const float* vn_b1  = (const float*)d_in[21];
    const float* vn_w2  = (const float*)d_in[22];
    const float* vn_b2  = (const float*)d_in[23];

    float* out = (float*)d_out;
    float* ef   = out;
    float* rel  = ef + (size_t)BATCH * SEQ * H;
    float* retr = rel + BATCH * H;
    float* sims = retr + BATCH * TOPK * H;
    float* tidx = sims + BATCH * N_ENT;
    float* ro   = tidx + BATCH * TOPK;
    float* vs   = ro + BATCH * H;

    float* ws = (float*)d_ws;
    size_t o = 0;
    float* pooled = ws + o; o += 8192;
    int*   idx_i  = (int*)(ws + o); o += 64;
    float* xin    = ws + o; o += 8 * 3 * H;
    float* partA  = ws + o; o += 48 * 8 * 2048;   // 786432 fl; also holds pool partials (512K)
    float* partB  = ws + o; o += 32 * 8 * 1024;   // 262144 fl
    unsigned short* w1t = (unsigned short*)(ws + o); o += (2048 * 1024) / 2;
    unsigned short* w2t = (unsigned short*)(ws + o); o += (2048 * 1024) / 2;
    unsigned short* hsb = (unsigned short*)(ws + o);

    long long avail = (long long)(ws_size / 4) - (long long)o;
    int chunk = (int)(avail / 1536);  // per row: 512 (hsb) + 1024 (mid) floats
    chunk &= ~255;                    // 256-row tiles
    int total = BATCH * SEQ;
    if (chunk > total) chunk = total;
    if (chunk < 256) chunk = 256;
    bool full = (chunk >= total);
    unsigned short* midb = hsb + (size_t)chunk * H;

    // pooling phase 1 (+ hs->bf16 fused when ws fits all rows); partials into partA
    pool1_kernel<<<dim3(64, BATCH), 256, 0, stream>>>(hs, partA, full ? hsb : nullptr);

    // weight prep (both transposes, one launch)
    transpose_both_kernel<<<4096, 256, 0, stream>>>(ee_w1, w1t, ee_w2, w2t);

    // pooling phase 2
    pool2_kernel<<<BATCH, 256, 0, stream>>>(partA, pooled);

    // relation encoder: partial -> fused(reduce+gelu)+partial -> LN
    mlp_partial_kernel<32><<<dim3(4, 32), 256, 0, stream>>>(pooled, H, re_w1, H, partA);
    mlp_partial_fused_kernel<32><<<dim3(4, 32), 256, 0, stream>>>(partA, H, 32, re_b1,
                                                                  re_w2, H, partB);
    mlp_reduce_ln_kernel<<<BATCH, 1024, 0, stream>>>(partB, re_b2, re_g, re_be, rel, 32);

    sim_kernel<<<250, 256, 0, stream>>>(rel, ent, sims);
    topk_kernel<<<BATCH, 256, 0, stream>>>(sims, tidx, idx_i);
    gather_concat_kernel<<<BATCH, 1024, 0, stream>>>(ent, idx_i, rel, pooled, retr, xin);

    // reasoning network
    mlp_partial_kernel<64><<<dim3(8, 48), 256, 0, stream>>>(xin, 3 * H, rn_w1, 2 * H, partA);
    mlp_partial_fused_kernel<64><<<dim3(4, 32), 256, 0, stream>>>(partA, 2 * H, 48, rn_b1,
                                                                  rn_w2, H, partB);
    mlp_reduce_ln_kernel<<<BATCH, 1024, 0, stream>>>(partB, rn_b2, rn_g, rn_be, ro, 32);

    // validation network
    mlp_partial_kernel<64><<<dim3(2, 16), 256, 0, stream>>>(ro, H, vn_w1, 512, partA);
    vn_final_kernel<<<BATCH, 512, 0, stream>>>(partA, vn_b1, vn_w2, vn_b2, vs, 16);

    // entity encoder (bf16 MFMA, 256^2 deep-pipelined)
    for (int r0 = 0; r0 < total; r0 += chunk) {
        int m = total - r0;
        if (m > chunk) m = chunk;
        if (!full) {
            int nconv = m * H;
            f2bf_kernel<<<(nconv / 4 + 255) / 256, 256, 0, stream>>>(hs + (size_t)r0 * H, hsb, nconv);
        }
        unsigned short* a1 = full ? (hsb + (size_t)r0 * H) : hsb;
        gemm256_8ph<1><<<(m / 256) * (2048 / 256), 512, 0, stream>>>(a1, w1t, ee_b1, midb,
                                                                     m, 2048, 1024);
        gemm256_8ph<0><<<(m / 256) * (1024 / 256), 512, 0, stream>>>(midb, w2t, ee_b2,
                                                                     ef + (size_t)r0 * H,
                                                                     m, 1024, 2048);
    }
    ln_rows_kernel<<<total, 256, 0, stream>>>(ef, ee_g, ee_be);
}